// Round 3
// baseline (724.806 us; speedup 1.0000x reference)
//
#include <hip/hip_runtime.h>
#include <hip/hip_bf16.h>

#define NE      800000
#define BM      128          // edges per tile
#define XPITCH  200          // bf16 elems per LDS row (400 B stride)
#define NTILE   (NE / BM)    // 6250
#define GRID    256

typedef __attribute__((ext_vector_type(8))) short short8;   // 8 x bf16
typedef __attribute__((ext_vector_type(4))) float f32x4;

// f32 -> bf16 bits, round-to-nearest-even
__device__ __forceinline__ ushort f2b(float f) {
    unsigned int u = __float_as_uint(f);
    return (ushort)((u + 0x7FFFu + ((u >> 16) & 1u)) >> 16);
}

// Wave grid: 8 waves = 2 row-groups (wr) x 4 col-groups (wc).
// GEMM1: wave owns rows wr*64..+63 (4 m-tiles), cols wc*48..+47 (3 n-tiles).
// GEMM2: wave owns rows wr*64..+63, cols wc*16..+15 (1 n-tile).
// W1/W2 fragments are tile-invariant -> held in registers (72+24 VGPR).
__global__ __launch_bounds__(512, 2)
void fused_edge_kernel(const float* __restrict__ nf, const float* __restrict__ ef,
                       const int* __restrict__ ei,
                       const float* __restrict__ W1, const float* __restrict__ b1,
                       const float* __restrict__ gamma, const float* __restrict__ beta,
                       const float* __restrict__ W2, const float* __restrict__ b2,
                       float* __restrict__ out)
{
    __shared__ __align__(16) ushort XH[BM * XPITCH];  // X(i) then H(i) then X(i+1)
    __shared__ float2 sums[BM * 4];                   // per (row, wc) partial (s, q)
    __shared__ float2 musr[BM];                       // per row (mean, rsqrt)
    __shared__ int    idxs[BM * 2];

    const int tid  = threadIdx.x;
    const int w    = tid >> 6;
    const int lane = tid & 63;
    const int lrow = lane & 15;
    const int lg   = lane >> 4;
    const int wr   = w >> 2;            // 0..1
    const int wc   = w & 3;             // 0..3
    const int rowbase = wr * 64;

    // ---- one-time: W fragments -> registers ----
    short8 w1f[3][6], w2f[6];
    #pragma unroll
    for (int tl = 0; tl < 3; ++tl) {
        int c = wc * 48 + tl * 16 + lrow;
        #pragma unroll
        for (int k = 0; k < 6; ++k) {
            const float* p = W1 + (size_t)(k * 32 + lg * 8) * 192 + c;
            #pragma unroll
            for (int j = 0; j < 8; ++j) w1f[tl][k][j] = (short)f2b(p[(size_t)j * 192]);
        }
    }
    {
        int c2 = wc * 16 + lrow;
        #pragma unroll
        for (int k = 0; k < 6; ++k) {
            const float* p = W2 + (size_t)(k * 32 + lg * 8) * 64 + c2;
            #pragma unroll
            for (int j = 0; j < 8; ++j) w2f[k][j] = (short)f2b(p[(size_t)j * 64]);
        }
    }
    float b1v[3], gv[3], bev[3];
    #pragma unroll
    for (int tl = 0; tl < 3; ++tl) {
        int c = wc * 48 + tl * 16 + lrow;
        b1v[tl] = b1[c]; gv[tl] = gamma[c]; bev[tl] = beta[c];
    }
    const float b2v = b2[wc * 16 + lrow];

    // ---- prologue: stage X(tile0) synchronously ----
    int tile = blockIdx.x;
    {
        const int e0 = tile * BM;
        if (tid < 256) idxs[(tid & 127) * 2 + (tid >> 7)] = ei[(tid >> 7) * NE + e0 + (tid & 127)];
        __syncthreads();
        #pragma unroll
        for (int j = 0; j < 12; ++j) {
            int fi = j * 512 + tid, le = fi / 48, c4 = fi - le * 48;
            int2 rc = *(const int2*)&idxs[le * 2];
            const float* src;
            if (c4 < 16)      src = nf + (size_t)rc.x * 64 + c4 * 4;
            else if (c4 < 32) src = nf + (size_t)rc.y * 64 + (c4 - 16) * 4;
            else              src = ef + (size_t)(e0 + le) * 64 + (c4 - 32) * 4;
            float4 v = *(const float4*)src;
            uint2 pk;
            pk.x = f2b(v.x) | ((unsigned)f2b(v.y) << 16);
            pk.y = f2b(v.z) | ((unsigned)f2b(v.w) << 16);
            *(uint2*)&XH[le * XPITCH + c4 * 4] = pk;
        }
        __syncthreads();
    }

    for (; tile < NTILE; tile += GRID) {
        const int e0 = tile * BM;
        const int tnext = tile + GRID;
        const bool hasNext = tnext < NTILE;
        const int e1 = hasNext ? tnext * BM : 0;

        // prefetch next tile's indices (latency hides under GEMM1)
        int idxnew = 0;
        if (hasNext && tid < 256) idxnew = ei[(tid >> 7) * NE + e1 + (tid & 127)];

        // ---- GEMM1: acc1[m][tl] over k, A from LDS, B from registers ----
        f32x4 acc1[4][3];
        #pragma unroll
        for (int m = 0; m < 4; ++m)
            #pragma unroll
            for (int tl = 0; tl < 3; ++tl)
                acc1[m][tl] = (f32x4){0.f, 0.f, 0.f, 0.f};
        #pragma unroll
        for (int k = 0; k < 6; ++k) {
            short8 a[4];
            #pragma unroll
            for (int m = 0; m < 4; ++m)
                a[m] = *(const short8*)&XH[(rowbase + m * 16 + lrow) * XPITCH + k * 32 + lg * 8];
            #pragma unroll
            for (int m = 0; m < 4; ++m)
                #pragma unroll
                for (int tl = 0; tl < 3; ++tl)
                    acc1[m][tl] = __builtin_amdgcn_mfma_f32_16x16x32_bf16(a[m], w1f[tl][k], acc1[m][tl], 0, 0, 0);
        }

        // ---- LN partials: +b1, per-lane sum over 3 cols, 16-lane reduce ----
        #pragma unroll
        for (int m = 0; m < 4; ++m) {
            #pragma unroll
            for (int rr = 0; rr < 4; ++rr) {
                float s = 0.f, q = 0.f;
                #pragma unroll
                for (int tl = 0; tl < 3; ++tl) {
                    float v = acc1[m][tl][rr] + b1v[tl];
                    acc1[m][tl][rr] = v;
                    s += v; q += v * v;
                }
                #pragma unroll
                for (int msk = 1; msk < 16; msk <<= 1) {
                    s += __shfl_xor(s, msk, 64);
                    q += __shfl_xor(q, msk, 64);
                }
                if (lrow == 0)
                    sums[(rowbase + m * 16 + lg * 4 + rr) * 4 + wc] = make_float2(s, q);
            }
        }
        __syncthreads();                       // B1: sums visible, GEMM1 reads done
        if (tid < 128) {
            float2 a0 = sums[tid * 4 + 0], a1 = sums[tid * 4 + 1];
            float2 a2 = sums[tid * 4 + 2], a3 = sums[tid * 4 + 3];
            float s = a0.x + a1.x + a2.x + a3.x;
            float q = a0.y + a1.y + a2.y + a3.y;
            float mean = s * (1.f / 192.f);
            float var  = q * (1.f / 192.f) - mean * mean;
            musr[tid] = make_float2(mean, rsqrtf(var + 1e-5f));
        }
        __syncthreads();                       // B2: musr visible

        // ---- apply LN + relu -> H (bf16) into XH; stash next idx ----
        #pragma unroll
        for (int m = 0; m < 4; ++m) {
            #pragma unroll
            for (int rr = 0; rr < 4; ++rr) {
                int row = rowbase + m * 16 + lg * 4 + rr;
                float2 mr = musr[row];
                #pragma unroll
                for (int tl = 0; tl < 3; ++tl) {
                    float v = (acc1[m][tl][rr] - mr.x) * mr.y * gv[tl] + bev[tl];
                    XH[row * XPITCH + wc * 48 + tl * 16 + lrow] = f2b(fmaxf(v, 0.f));
                }
            }
        }
        if (hasNext && tid < 256) idxs[(tid & 127) * 2 + (tid >> 7)] = idxnew;
        __syncthreads();                       // B3: H + idxs visible

        // ---- issue next tile's gather loads (stay in flight across GEMM2) ----
        float4 xv[12];
        if (hasNext) {
            #pragma unroll
            for (int j = 0; j < 12; ++j) {
                int fi = j * 512 + tid, le = fi / 48, c4 = fi - le * 48;
                int2 rc = *(const int2*)&idxs[le * 2];
                const float* src;
                if (c4 < 16)      src = nf + (size_t)rc.x * 64 + c4 * 4;
                else if (c4 < 32) src = nf + (size_t)rc.y * 64 + (c4 - 16) * 4;
                else              src = ef + (size_t)(e1 + le) * 64 + (c4 - 32) * 4;
                xv[j] = *(const float4*)src;
            }
        }
        // ef residual prefetch (L2-hot: same rows read during gather of tile i)
        float efv[16];
        #pragma unroll
        for (int m = 0; m < 4; ++m)
            #pragma unroll
            for (int rr = 0; rr < 4; ++rr) {
                int row = rowbase + m * 16 + lg * 4 + rr;
                efv[m * 4 + rr] = ef[(size_t)(e0 + row) * 64 + wc * 16 + lrow];
            }

        // ---- GEMM2: acc2[m] over k, A = H from LDS, B = W2 registers ----
        f32x4 acc2[4];
        #pragma unroll
        for (int m = 0; m < 4; ++m) acc2[m] = (f32x4){0.f, 0.f, 0.f, 0.f};
        #pragma unroll
        for (int k = 0; k < 6; ++k) {
            short8 h[4];
            #pragma unroll
            for (int m = 0; m < 4; ++m)
                h[m] = *(const short8*)&XH[(rowbase + m * 16 + lrow) * XPITCH + k * 32 + lg * 8];
            #pragma unroll
            for (int m = 0; m < 4; ++m)
                acc2[m] = __builtin_amdgcn_mfma_f32_16x16x32_bf16(h[m], w2f[k], acc2[m], 0, 0, 0);
        }

        // ---- epilogue: + b2 + residual, store f32 ----
        #pragma unroll
        for (int m = 0; m < 4; ++m)
            #pragma unroll
            for (int rr = 0; rr < 4; ++rr) {
                int row = rowbase + m * 16 + lg * 4 + rr;
                out[(size_t)(e0 + row) * 64 + wc * 16 + lrow] = acc2[m][rr] + b2v + efv[m * 4 + rr];
            }

        __syncthreads();                       // B4: all H reads done
        if (hasNext) {
            #pragma unroll
            for (int j = 0; j < 12; ++j) {
                int fi = j * 512 + tid, le = fi / 48, c4 = fi - le * 48;
                uint2 pk;
                pk.x = f2b(xv[j].x) | ((unsigned)f2b(xv[j].y) << 16);
                pk.y = f2b(xv[j].z) | ((unsigned)f2b(xv[j].w) << 16);
                *(uint2*)&XH[le * XPITCH + c4 * 4] = pk;
            }
        }
        __syncthreads();                       // B5: X(i+1) visible
    }
}

extern "C" void kernel_launch(void* const* d_in, const int* in_sizes, int n_in,
                              void* d_out, int out_size, void* d_ws, size_t ws_size,
                              hipStream_t stream) {
    const float* nf    = (const float*)d_in[0];
    const float* ef    = (const float*)d_in[1];
    const int*   ei    = (const int*)d_in[2];
    const float* W1    = (const float*)d_in[3];
    const float* b1    = (const float*)d_in[4];
    const float* gamma = (const float*)d_in[5];
    const float* beta  = (const float*)d_in[6];
    const float* W2    = (const float*)d_in[7];
    const float* b2    = (const float*)d_in[8];
    float* out = (float*)d_out;

    hipLaunchKernelGGL(fused_edge_kernel, dim3(GRID), dim3(512), 0, stream,
                       nf, ef, ei, W1, b1, gamma, beta, W2, b2, out);
}